// Round 5
// baseline (898.053 us; speedup 1.0000x reference)
//
#include <hip/hip_runtime.h>
#include <cstdint>
#include <cstddef>

// ---- fixed problem shape (from setup_inputs) ------------------------------
#define E_      24          // experts
#define D_IN    1024
#define D_HID   4096
#define HGRP    4           // groups (H)
#define BSZ     4
#define SEQ     2048
#define NSUB    512         // seq / HGRP
#define S_      2048        // tokens per group = BSZ*NSUB
#define NTOKG   8192        // HGRP * S_
#define CAP     171         // ceil(2*S_/E_)
#define MR      768         // per-expert rows, 4*CAP=684 padded to 3*256
#define MTILE   3           // M tiles of 256
#define KSPL2   4           // GEMM2 K-split (chunks of 1024)

typedef __attribute__((ext_vector_type(4))) float          f32x4;
typedef __attribute__((ext_vector_type(4))) unsigned short u16x4;
typedef __attribute__((ext_vector_type(8))) unsigned short u16x8;
typedef __attribute__((ext_vector_type(4))) unsigned int   u32x4;
typedef __attribute__((ext_vector_type(8))) short          s16x8;

__device__ __forceinline__ unsigned short f2bf(float f) {   // RNE f32->bf16
  unsigned int u = __float_as_uint(f);
  u += 0x7fffu + ((u >> 16) & 1u);
  return (unsigned short)(u >> 16);
}
__device__ __forceinline__ float bf2f(unsigned short v) {
  return __uint_as_float(((unsigned int)v) << 16);
}

// ---- 1) gating: logits = x_row @ Wg, softmax, top-2 (first-max ties) -----
__global__ __launch_bounds__(64)
void k_gating(const float* __restrict__ x, const float* __restrict__ Wg,
              int* __restrict__ tokE1, int* __restrict__ tokE2,
              float* __restrict__ tokG1, float* __restrict__ tokG2) {
  int tg = blockIdx.x;                 // h*S_ + s
  int h = tg >> 11, s = tg & 2047;
  int bi = s >> 9, ni = s & 511;
  const float* xr = x + ((size_t)bi*SEQ + (size_t)h*NSUB + ni) * D_IN;
  int lane = threadIdx.x;
  float acc[E_];
  #pragma unroll
  for (int e = 0; e < E_; ++e) acc[e] = 0.f;
  #pragma unroll
  for (int it = 0; it < D_IN/256; ++it) {
    f32x4 xv = *(const f32x4*)(xr + it*256 + lane*4);
    #pragma unroll
    for (int j = 0; j < 4; ++j) {
      float xs = xv[j];
      const float* wrow = Wg + (size_t)(it*256 + lane*4 + j) * E_;
      #pragma unroll
      for (int e = 0; e < E_; ++e) acc[e] += xs * wrow[e];
    }
  }
  #pragma unroll
  for (int e = 0; e < E_; ++e) {
    float v = acc[e];
    v += __shfl_xor(v, 32); v += __shfl_xor(v, 16); v += __shfl_xor(v, 8);
    v += __shfl_xor(v, 4);  v += __shfl_xor(v, 2);  v += __shfl_xor(v, 1);
    acc[e] = v;
  }
  if (lane == 0) {
    float mx = acc[0];
    #pragma unroll
    for (int e = 1; e < E_; ++e) mx = fmaxf(mx, acc[e]);
    float den = 0.f;
    #pragma unroll
    for (int e = 0; e < E_; ++e) den += expf(acc[e] - mx);
    int i1 = 0; float v1 = acc[0];
    #pragma unroll
    for (int e = 1; e < E_; ++e) if (acc[e] > v1) { v1 = acc[e]; i1 = e; }  // first max
    int i2 = -1; float v2 = -3.4e38f;
    #pragma unroll
    for (int e = 0; e < E_; ++e) if (e != i1 && acc[e] > v2) { v2 = acc[e]; i2 = e; }
    tokE1[tg] = i1; tokE2[tg] = i2;
    tokG1[tg] = expf(v1 - mx) / den;   // raw softmax probs; renorm after drops
    tokG2[tg] = expf(v2 - mx) / den;
  }
}

// ---- 2) slot map init ----------------------------------------------------
__global__ void k_init_slots(int* __restrict__ slotTok) {
  slotTok[blockIdx.x*256 + threadIdx.x] = -1;
}

// ---- 3) capacity scan: exact cumsum order, loc2 offset by RAW top1 totals
__global__ __launch_bounds__(64)
void k_scan(const int* __restrict__ tokE1, const int* __restrict__ tokE2,
            float* __restrict__ tokG1, float* __restrict__ tokG2,
            int* __restrict__ tokP1, int* __restrict__ tokP2,
            int* __restrict__ slotTok) {
  int h = blockIdx.x;
  int lane = threadIdx.x;
  __shared__ int cnt[64][E_];
  __shared__ int tot1[E_];
  const int CH = S_/64;                           // 32 tokens per lane chunk
  const int* e1 = tokE1 + h*S_;
  const int* e2 = tokE2 + h*S_;
  // choice 1
  #pragma unroll
  for (int e = 0; e < E_; ++e) cnt[lane][e] = 0;
  __syncthreads();
  for (int k = 0; k < CH; ++k) cnt[lane][e1[lane*CH + k]]++;
  __syncthreads();
  if (lane < E_) {
    int run = 0;
    for (int j = 0; j < 64; ++j) { int t = cnt[j][lane]; cnt[j][lane] = run; run += t; }
    tot1[lane] = run;                             // raw (pre-capacity) total
  }
  __syncthreads();
  for (int k = 0; k < CH; ++k) {
    int s = lane*CH + k;
    int e = e1[s];
    int p = cnt[lane][e]++;
    int tg = h*S_ + s;
    if (p < CAP) { tokP1[tg] = p; slotTok[e*MR + h*CAP + p] = tg; }
    else         { tokP1[tg] = -1; }
  }
  __syncthreads();
  // choice 2 (offset by raw tot1)
  #pragma unroll
  for (int e = 0; e < E_; ++e) cnt[lane][e] = 0;
  __syncthreads();
  for (int k = 0; k < CH; ++k) cnt[lane][e2[lane*CH + k]]++;
  __syncthreads();
  if (lane < E_) {
    int run = tot1[lane];
    for (int j = 0; j < 64; ++j) { int t = cnt[j][lane]; cnt[j][lane] = run; run += t; }
  }
  __syncthreads();
  for (int k = 0; k < CH; ++k) {
    int s = lane*CH + k;
    int e = e2[s];
    int p = cnt[lane][e]++;
    int tg = h*S_ + s;
    if (p < CAP) { tokP2[tg] = p; slotTok[e*MR + h*CAP + p] = tg; }
    else         { tokP2[tg] = -1; }
  }
  __syncthreads();
  // gate renorm after capacity drops (den cancels softmax norm exactly)
  for (int k = 0; k < CH; ++k) {
    int tg = h*S_ + k*64 + lane;
    float g1 = (tokP1[tg] >= 0) ? tokG1[tg] : 0.f;
    float g2 = (tokP2[tg] >= 0) ? tokG2[tg] : 0.f;
    float den = fmaxf(g1 + g2, 1e-9f);
    tokG1[tg] = g1 / den;
    tokG2[tg] = g2 / den;
  }
}

// ---- 4) gather tokens -> A1 bf16 [E][MR][D_IN], XOR swizzle baked --------
__global__ __launch_bounds__(256)
void k_gather1(const float* __restrict__ x, const int* __restrict__ slotTok,
               unsigned short* __restrict__ A1) {
  int row = blockIdx.x;                // e*MR + r ; row&7 == r&7 (MR%8==0)
  int tok = slotTok[row];
  int t = threadIdx.x;
  int k = t*4;
  int ba = ((k & 63)*2) ^ ((row & 7) << 4);       // swizzle within 64-elem chunk
  char* dst = (char*)A1 + (size_t)row*(D_IN*2) + (size_t)(k >> 6)*128 + ba;
  u16x4 pk;
  if (tok >= 0) {
    int h = tok >> 11, s = tok & 2047;
    int bi = s >> 9, ni = s & 511;
    const float* xr = x + ((size_t)bi*SEQ + (size_t)h*NSUB + ni) * D_IN;
    f32x4 v = *(const f32x4*)(xr + k);
    pk.x = f2bf(v.x); pk.y = f2bf(v.y); pk.z = f2bf(v.z); pk.w = f2bf(v.w);
  } else {
    pk.x = 0; pk.y = 0; pk.z = 0; pk.w = 0;
  }
  *(u16x4*)dst = pk;
}

// ---- 4b) W fp32 [E][K][N] -> Wt bf16 [E][N][K] transposed, swizzle baked -
template<int K, int N>
__global__ __launch_bounds__(256)
void k_cvtW(const float* __restrict__ W, unsigned short* __restrict__ Wt) {
  const int NB = N/64, KB = K/64;
  int bid = blockIdx.x;
  int kb = bid % KB;
  int rem = bid / KB;
  int nb = rem % NB;
  int e  = rem / NB;
  __shared__ float lds[64][65];
  int t = threadIdx.x;
  // load: 64k x 64n tile, coalesced along n
  int kl = t >> 2, ng = (t & 3) * 16;
  const float* src = W + ((size_t)e*K + (size_t)kb*64 + kl)*N + (size_t)nb*64 + ng;
  f32x4 v0 = *(const f32x4*)(src);
  f32x4 v1 = *(const f32x4*)(src + 4);
  f32x4 v2 = *(const f32x4*)(src + 8);
  f32x4 v3 = *(const f32x4*)(src + 12);
  #pragma unroll
  for (int j = 0; j < 4; ++j) lds[ng +  0 + j][kl] = v0[j];
  #pragma unroll
  for (int j = 0; j < 4; ++j) lds[ng +  4 + j][kl] = v1[j];
  #pragma unroll
  for (int j = 0; j < 4; ++j) lds[ng +  8 + j][kl] = v2[j];
  #pragma unroll
  for (int j = 0; j < 4; ++j) lds[ng + 12 + j][kl] = v3[j];
  __syncthreads();
  // store: row n, 16 k-elems per thread, swizzled within the 128B chunk
  int nl = t >> 2, kg = (t & 3) * 16;
  u16x8 c0, c1;
  #pragma unroll
  for (int j = 0; j < 8; ++j) {
    c0[j] = f2bf(lds[nl][kg + j]);
    c1[j] = f2bf(lds[nl][kg + 8 + j]);
  }
  char* dst = (char*)Wt + ((size_t)e*N + (size_t)nb*64 + nl)*(K*2) + (size_t)kb*128;
  int sw = (nl & 7) << 4;
  *(u16x8*)(dst + ((kg*2)      ^ sw)) = c0;
  *(u16x8*)(dst + ((kg*2 + 16) ^ sw)) = c1;
}

// ---- 5) GEMM: Out[e](+kc partial) = A[e] @ Wt[e]^T + bias[e]
// 256x256 tile, BK=64, 8 waves (512 thr), wave tile 128x64, 16x16x32 bf16.
// Both operands bf16, pre-swizzled in global; staged by global_load_lds x16.
// Per K-tile: all 8 stage-insts for tile kt+1 issue at phase-1 top (max
// latency cover), 4 phases {frags | raw s_barrier | lgkm0 | 16 MFMA | bar},
// single correctness drain = tile-end __syncthreads (vmcnt0+lgkm0+barrier).
template<int KROW, int KCHUNK, int N>
__global__ __launch_bounds__(512, 2)
void k_gemm(const unsigned short* __restrict__ A, const unsigned short* __restrict__ Wt,
            const float* __restrict__ bias, unsigned short* __restrict__ Out) {
  const int NT = N / 256;
  const int KSPLIT = KROW / KCHUNK;
  const int NKT = KCHUNK / 64;          // 16
  int cpx = gridDim.x >> 3;             // gridDim % 8 == 0
  int lb = blockIdx.x;
  int bid = (lb & 7) * cpx + (lb >> 3); // XCD-bijective swizzle
  int mt  = bid % MTILE;                // mt innermost: 3 blocks share W panel
  int rem = bid / MTILE;
  int kc  = rem % KSPLIT;
  rem /= KSPLIT;
  int nt  = rem % NT;
  int e   = rem / NT;

  const char* Ab = (const char*)A  + ((size_t)e*MR + (size_t)mt*256) * (KROW*2);
  const char* Bb = (const char*)Wt + ((size_t)e*N  + (size_t)nt*256) * (KROW*2);
  size_t kbase = (size_t)kc * (KCHUNK*2);

  __shared__ unsigned short As0[256*64];   // 32 KB each
  __shared__ unsigned short As1[256*64];
  __shared__ unsigned short Bs0[256*64];
  __shared__ unsigned short Bs1[256*64];

  int tid  = threadIdx.x;
  int lane = tid & 63;
  int wid  = tid >> 6;
  int wr = wid >> 2, wc = wid & 3;        // wave -> 128(M) x 64(N) sub-tile

  f32x4 acc[8][4];
  #pragma unroll
  for (int i = 0; i < 8; ++i)
    #pragma unroll
    for (int j = 0; j < 4; ++j) acc[i][j] = (f32x4)0.f;

  auto stage = [&](int kt2, unsigned short* As, unsigned short* Bs) {
    size_t koff = kbase + (size_t)kt2*128;
    #pragma unroll
    for (int i = 0; i < 4; ++i) {
      int L = i*8192 + tid*16;
      __builtin_amdgcn_global_load_lds(
          (const __attribute__((address_space(1))) void*)(Ab + (size_t)(L >> 7)*(KROW*2) + koff + (L & 127)),
          (__attribute__((address_space(3))) void*)((char*)As + L), 16, 0, 0);
    }
    #pragma unroll
    for (int i = 0; i < 4; ++i) {
      int L = i*8192 + tid*16;
      __builtin_amdgcn_global_load_lds(
          (const __attribute__((address_space(1))) void*)(Bb + (size_t)(L >> 7)*(KROW*2) + koff + (L & 127)),
          (__attribute__((address_space(3))) void*)((char*)Bs + L), 16, 0, 0);
    }
  };
  auto fragsA = [&](const unsigned short* As, int ra, int ks, s16x8* afr) {
    int kb = ks*64 + (lane >> 4)*16;
    #pragma unroll
    for (int i = 0; i < 4; ++i) {
      int r = wr*128 + ra*64 + i*16 + (lane & 15);
      afr[i] = *(const s16x8*)((const char*)As + r*128 + (kb ^ ((r & 7) << 4)));
    }
  };
  auto fragsB = [&](const unsigned short* Bs, int ks, s16x8* bfr) {
    int kb = ks*64 + (lane >> 4)*16;
    #pragma unroll
    for (int j = 0; j < 4; ++j) {
      int c = wc*64 + j*16 + (lane & 15);
      bfr[j] = *(const s16x8*)((const char*)Bs + c*128 + (kb ^ ((c & 7) << 4)));
    }
  };
  auto mfma16 = [&](int ra, const s16x8* afr, const s16x8* bfr) {
    __builtin_amdgcn_s_setprio(1);
    #pragma unroll
    for (int i = 0; i < 4; ++i)
      #pragma unroll
      for (int j = 0; j < 4; ++j)
        acc[ra*4+i][j] = __builtin_amdgcn_mfma_f32_16x16x32_bf16(afr[i], bfr[j], acc[ra*4+i][j], 0, 0, 0);
    __builtin_amdgcn_s_setprio(0);
  };

  auto tile = [&](int t, const unsigned short* Ac, const unsigned short* Bc,
                  unsigned short* An, unsigned short* Bn) {
    int tn = (t + 1 < NKT) ? t + 1 : t;     // clamped dup stage on last tile
    s16x8 afr[4], bfr[4];
    // ph1: issue ALL next-tile staging first (max latency slack)
    stage(tn, An, Bn);
    fragsA(Ac, 0, 0, afr); fragsB(Bc, 0, bfr);
    __builtin_amdgcn_s_barrier();
    asm volatile("s_waitcnt lgkmcnt(0)" ::: "memory");
    __builtin_amdgcn_sched_barrier(0);
    mfma16(0, afr, bfr);
    __builtin_amdgcn_s_barrier();
    // ph2 (reuse bfr)
    fragsA(Ac, 1, 0, afr);
    __builtin_amdgcn_s_barrier();
    asm volatile("s_waitcnt lgkmcnt(0)" ::: "memory");
    __builtin_amdgcn_sched_barrier(0);
    mfma16(1, afr, bfr);
    __builtin_amdgcn_s_barrier();
    // ph3
    fragsA(Ac, 0, 1, afr); fragsB(Bc, 1, bfr);
    __builtin_amdgcn_s_barrier();
    asm volatile("s_waitcnt lgkmcnt(0)" ::: "memory");
    __builtin_amdgcn_sched_barrier(0);
    mfma16(0, afr, bfr);
    __builtin_amdgcn_s_barrier();
    // ph4 (reuse bfr)
    fragsA(Ac, 1, 1, afr);
    __builtin_amdgcn_s_barrier();
    asm volatile("s_waitcnt lgkmcnt(0)" ::: "memory");
    __builtin_amdgcn_sched_barrier(0);
    mfma16(1, afr, bfr);
    __syncthreads();                        // tile-end drain: vmcnt0+lgkm0+bar
  };

  // prologue: stage tile 0
  stage(0, As0, Bs0);
  __syncthreads();
  for (int kt = 0; kt < NKT; kt += 2) {     // NKT even
    tile(kt,     As0, Bs0, As1, Bs1);
    tile(kt + 1, As1, Bs1, As0, Bs0);
  }

  // epilogue: +bias (only kc==0), bf16 store (plain layout, partial kc)
  unsigned short* Op = Out + (size_t)kc * ((size_t)E_*MR*N);
  #pragma unroll
  for (int j = 0; j < 4; ++j) {
    int col = nt*256 + wc*64 + j*16 + (lane & 15);
    float bv = (kc == 0) ? bias[(size_t)e*N + col] : 0.f;
    #pragma unroll
    for (int i = 0; i < 8; ++i) {
      int rowb = mt*256 + wr*128 + i*16 + (lane >> 4)*4;
      #pragma unroll
      for (int r = 0; r < 4; ++r) {
        float v = acc[i][j][r] + bv;
        Op[(size_t)e*MR*N + (size_t)(rowb + r)*N + col] = f2bf(v);
      }
    }
  }
}

// ---- 6) zero A2 rows with no token (incl. pad rows) ----------------------
__global__ __launch_bounds__(256)
void k_zero_empty(const int* __restrict__ slotTok, unsigned short* __restrict__ A2) {
  int row = blockIdx.x;
  if (slotTok[row] >= 0) return;
  u32x4 z = (u32x4)0u;
  char* base = (char*)A2 + (size_t)row*(D_HID*2) + threadIdx.x*32;
  *(u32x4*)base = z;
  *(u32x4*)(base + 16) = z;
}

// ---- 7) combine g1*H1[r1]+g2*H1[r2] -> LN -> ReLU -> redispatch into A2 --
__global__ __launch_bounds__(256)
void k_combine_ln(const unsigned short* __restrict__ H1,
                  const int* __restrict__ tokE1, const int* __restrict__ tokE2,
                  const int* __restrict__ tokP1, const int* __restrict__ tokP2,
                  const float* __restrict__ tokG1, const float* __restrict__ tokG2,
                  const float* __restrict__ lnw, const float* __restrict__ lnb,
                  unsigned short* __restrict__ A2) {
  int tg = blockIdx.x;
  int h = tg >> 11;
  int p1 = tokP1[tg], p2 = tokP2[tg];
  if (p1 < 0 && p2 < 0) return;                       // no slots; rows zeroed
  float g1 = tokG1[tg], g2 = tokG2[tg];
  long r1 = (p1 >= 0) ? ((long)tokE1[tg]*MR + h*CAP + p1) : -1;
  long r2 = (p2 >= 0) ? ((long)tokE2[tg]*MR + h*CAP + p2) : -1;
  int t = threadIdx.x;
  float v[16];
  float sum = 0.f, sq = 0.f;
  #pragma unroll
  for (int u = 0; u < 4; ++u) {
    int f = u*1024 + t*4;
    float a0 = 0.f, a1 = 0.f, a2 = 0.f, a3 = 0.f;
    if (r1 >= 0) {
      u16x4 q = *(const u16x4*)(H1 + (size_t)r1*D_HID + f);
      a0 += g1*bf2f(q.x); a1 += g1*bf2f(q.y); a2 += g1*bf2f(q.z); a3 += g1*bf2f(q.w);
    }
    if (r2 >= 0) {
      u16x4 q = *(const u16x4*)(H1 + (size_t)r2*D_HID + f);
      a0 += g2*bf2f(q.x); a1 += g2*bf2f(q.y); a2 += g2*bf2f(q.z); a3 += g2*bf2f(q.w);
    }
    v[u*4+0] = a0; v[u*4+1] = a1; v[u*4+2] = a2; v[u*4+3] = a3;
    sum += a0 + a1 + a2 + a3;
    sq  += a0*a0 + a1*a1 + a2*a2 + a3*a3;
  }
  #pragma unroll
  for (int o = 32; o; o >>= 1) { sum += __shfl_xor(sum, o); sq += __shfl_xor(sq, o); }
  __shared__ float redA[4], redB[4];
  int wid = t >> 6;
  if ((t & 63) == 0) { redA[wid] = sum; redB[wid] = sq; }
  __syncthreads();
  float S = redA[0] + redA[1] + redA[2] + redA[3];
  float Q = redB[0] + redB[1] + redB[2] + redB[3];
  float m = S * (1.f / D_HID);
  float var = Q * (1.f / D_HID) - m*m;
  float rs = rsqrtf(var + 1e-6f);
  #pragma unroll
  for (int u = 0; u < 4; ++u) {
    int f = u*1024 + t*4;
    u16x4 pk;
    float y0 = fmaxf((v[u*4+0]-m)*rs*lnw[h*D_HID+f+0] + lnb[h*D_HID+f+0], 0.f);
    float y1 = fmaxf((v[u*4+1]-m)*rs*lnw[h*D_HID+f+1] + lnb[h*D_HID+f+1], 0.f);
    float y2 = fmaxf((v[u*4+2]-m)*rs*lnw[h*D_HID+f+2] + lnb[h*D_HID+f+2], 0.f);
    float y3 = fmaxf((v[u*4+3]-m)*rs*lnw[h*D_HID+f+3] + lnb[h*D_HID+f+3], 0.f);
    pk.x = f2bf(y0); pk.y = f2bf(y1); pk.z = f2bf(y2); pk.w = f2bf(y3);
    int chunk = f >> 6;
    int ob = (f & 63)*2;
    if (r1 >= 0)
      *(u16x4*)((char*)A2 + (size_t)r1*(D_HID*2) + (size_t)chunk*128 + (ob ^ (((int)r1 & 7) << 4))) = pk;
    if (r2 >= 0)
      *(u16x4*)((char*)A2 + (size_t)r2*(D_HID*2) + (size_t)chunk*128 + (ob ^ (((int)r2 & 7) << 4))) = pk;
  }
}

// ---- 8) final: sum 4 GEMM2 partials + residual + LayerNorm ---------------
__global__ __launch_bounds__(256)
void k_final(const unsigned short* __restrict__ H2p, const float* __restrict__ x,
             const int* __restrict__ tokE1, const int* __restrict__ tokE2,
             const int* __restrict__ tokP1, const int* __restrict__ tokP2,
             const float* __restrict__ tokG1, const float* __restrict__ tokG2,
             const float* __restrict__ lnw, const float* __restrict__ lnb,
             float* __restrict__ out) {
  const size_t PSTR = (size_t)E_*MR*D_IN;
  int tg = blockIdx.x;
  int h = tg >> 11, s = tg & 2047;
  int bi = s >> 9, ni = s & 511;
  size_t xoff = ((size_t)bi*SEQ + (size_t)h*NSUB + ni) * D_IN;
  int p1 = tokP1[tg], p2 = tokP2[tg];
  float g1 = tokG1[tg], g2 = tokG2[tg];
  int t = threadIdx.x;
  int f = t*4;
  f32x4 xv = *(const f32x4*)(x + xoff + f);
  float v0 = xv.x, v1 = xv.y, v2 = xv.z, v3 = xv.w;
  if (p1 >= 0) {
    size_t r1 = (size_t)tokE1[tg]*MR + h*CAP + p1;
    float a0 = 0.f, a1 = 0.f, a2 = 0.f, a3 = 0.f;
    #pragma unroll
    for (int p = 0; p < KSPL2; ++p) {
      u16x4 q = *(const u16x4*)(H2p + p*PSTR + r1*D_IN + f);
      a0 += bf2f(q.x); a1 += bf2f(q.y); a2 += bf2f(q.z); a3 += bf2f(q.w);
    }
    v0 += g1*a0; v1 += g1*a1; v2 += g1*a2; v3 += g1*a3;
  }
  if (p2 >= 0) {
    size_t r2 = (size_t)tokE2[tg]*MR + h*CAP + p2;
    float a0 = 0.f, a1 = 0.f, a2 = 0.f, a3 = 0.f;
    #pragma unroll
    for (int p = 0; p < KSPL2; ++p) {
      u16x4 q = *(const u16x4*)(H2p + p*PSTR + r2*D_IN + f);
      a0 += bf2f(q.x); a1 += bf2f(q.y); a2 += bf2f(q.z); a3 += bf2f(q.w);
    }
    v0 += g2*a0; v1 += g2*a1; v2 += g2*a2; v3 += g2*a3;
  }
  float sum = v0+v1+v2+v3, sq = v0*v0+v1*v1+v2*v2+v3*v3;
  #pragma unroll
  for (int o = 32; o; o >>= 1) { sum += __shfl_xor(sum, o); sq += __shfl_xor(sq, o); }
  __shared__ float redA[4], redB[4];
  int wid = t >> 6;
  if ((t & 63) == 0) { redA[wid] = sum; redB[wid] = sq; }
  __syncthreads();
  float S = redA[0] + redA[1] + redA[2] + redA[3];
  float Q = redB[0] + redB[1] + redB[2] + redB[3];
  float m = S * (1.f / D_IN);
  float var = Q * (1.f / D_IN) - m*m;
  float rs = rsqrtf(var + 1e-6f);
  f32x4 res;
  res.x = (v0 - m)*rs*lnw[f+0] + lnb[f+0];
  res.y = (v1 - m)*rs*lnw[f+1] + lnb[f+1];
  res.z = (v2 - m)*rs*lnw[f+2] + lnb[f+2];
  res.w = (v3 - m)*rs*lnw[f+3] + lnb[f+3];
  *(f32x4*)(out + xoff + f) = res;
}

// ---- launcher ------------------------------------------------------------
extern "C" void kernel_launch(void* const* d_in, const int* in_sizes, int n_in,
                              void* d_out, int out_size, void* d_ws, size_t ws_size,
                              hipStream_t stream) {
  const float* x    = (const float*)d_in[0];
  const float* Wg   = (const float*)d_in[1];
  const float* W1   = (const float*)d_in[2];
  const float* b1   = (const float*)d_in[3];
  const float* W2   = (const float*)d_in[4];
  const float* b2   = (const float*)d_in[5];
  const float* lnhw = (const float*)d_in[6];
  const float* lnhb = (const float*)d_in[7];
  const float* lnow = (const float*)d_in[8];
  const float* lnob = (const float*)d_in[9];
  float* out = (float*)d_out;
  (void)in_sizes; (void)n_in; (void)out_size; (void)ws_size;

  char* ws = (char*)d_ws;
  size_t off = 0;
  auto take = [&](size_t bytes) -> char* {
    char* p = ws + off;
    off += (bytes + 255) & ~(size_t)255;
    return p;
  };
  int*   tokE1 = (int*)take(NTOKG*sizeof(int));
  int*   tokE2 = (int*)take(NTOKG*sizeof(int));
  int*   tokP1 = (int*)take(NTOKG*sizeof(int));
  int*   tokP2 = (int*)take(NTOKG*sizeof(int));
  float* tokG1 = (float*)take(NTOKG*sizeof(float));
  float* tokG2 = (float*)take(NTOKG*sizeof(float));
  int*   slotTok = (int*)take((size_t)E_*MR*sizeof(int));
  unsigned short* A1 = (unsigned short*)take((size_t)E_*MR*D_IN*2);   //  37.7 MB
  unsigned short* H1 = (unsigned short*)take((size_t)E_*MR*D_HID*2);  // 151 MB (= 4x GEMM2 partials)
  unsigned short* A2 = (unsigned short*)take((size_t)E_*MR*D_HID*2);  // 151 MB
  unsigned short* Wt = (unsigned short*)take((size_t)E_*D_IN*D_HID*2);// 201 MB (shared W1t/W2t)
  unsigned short* H2p = H1;   // GEMM2 partials alias dead H1 (after combine_ln)

  k_init_slots<<<dim3(E_*MR/256), dim3(256), 0, stream>>>(slotTok);
  k_gating<<<dim3(NTOKG), dim3(64), 0, stream>>>(x, Wg, tokE1, tokE2, tokG1, tokG2);
  k_scan<<<dim3(HGRP), dim3(64), 0, stream>>>(tokE1, tokE2, tokG1, tokG2, tokP1, tokP2, slotTok);
  k_gather1<<<dim3(E_*MR), dim3(256), 0, stream>>>(x, slotTok, A1);
  k_cvtW<D_IN, D_HID><<<dim3(E_*(D_HID/64)*(D_IN/64)), dim3(256), 0, stream>>>(W1, Wt);
  k_gemm<D_IN, D_IN, D_HID><<<dim3(E_*(D_HID/256)*MTILE), dim3(512), 0, stream>>>(A1, Wt, b1, H1);
  k_zero_empty<<<dim3(E_*MR), dim3(256), 0, stream>>>(slotTok, A2);
  k_combine_ln<<<dim3(NTOKG), dim3(256), 0, stream>>>(H1, tokE1, tokE2, tokP1, tokP2,
                                                      tokG1, tokG2, lnhw, lnhb, A2);
  k_cvtW<D_HID, D_IN><<<dim3(E_*(D_IN/64)*(D_HID/64)), dim3(256), 0, stream>>>(W2, Wt);
  k_gemm<D_HID, D_IN, D_IN><<<dim3(E_*(D_IN/256)*MTILE*KSPL2), dim3(512), 0, stream>>>(A2, Wt, b2, H2p);
  k_final<<<dim3(NTOKG), dim3(256), 0, stream>>>(H2p, x, tokE1, tokE2, tokP1, tokP2,
                                                 tokG1, tokG2, lnow, lnob, out);
}

// Round 6
// 875.484 us; speedup vs baseline: 1.0258x; 1.0258x over previous
//
#include <hip/hip_runtime.h>
#include <cstdint>
#include <cstddef>

// ---- fixed problem shape (from setup_inputs) ------------------------------
#define E_      24          // experts
#define D_IN    1024
#define D_HID   4096
#define HGRP    4           // groups (H)
#define BSZ     4
#define SEQ     2048
#define NSUB    512         // seq / HGRP
#define S_      2048        // tokens per group = BSZ*NSUB
#define NTOKG   8192        // HGRP * S_
#define CAP     171         // ceil(2*S_/E_)
#define MR      768         // per-expert rows, 4*CAP=684 padded to 3*256
#define MTILE   3           // M tiles of 256
#define KSPL2   4           // GEMM2 K-split (chunks of 1024)

typedef __attribute__((ext_vector_type(4))) float          f32x4;
typedef __attribute__((ext_vector_type(4))) unsigned short u16x4;
typedef __attribute__((ext_vector_type(8))) unsigned short u16x8;
typedef __attribute__((ext_vector_type(4))) unsigned int   u32x4;
typedef __attribute__((ext_vector_type(8))) short          s16x8;

__device__ __forceinline__ unsigned short f2bf(float f) {   // RNE f32->bf16
  unsigned int u = __float_as_uint(f);
  u += 0x7fffu + ((u >> 16) & 1u);
  return (unsigned short)(u >> 16);
}
__device__ __forceinline__ float bf2f(unsigned short v) {
  return __uint_as_float(((unsigned int)v) << 16);
}

// ---- 1) gating: logits = x_row @ Wg, softmax, top-2 (first-max ties) -----
__global__ __launch_bounds__(64)
void k_gating(const float* __restrict__ x, const float* __restrict__ Wg,
              int* __restrict__ tokE1, int* __restrict__ tokE2,
              float* __restrict__ tokG1, float* __restrict__ tokG2) {
  int tg = blockIdx.x;                 // h*S_ + s
  int h = tg >> 11, s = tg & 2047;
  int bi = s >> 9, ni = s & 511;
  const float* xr = x + ((size_t)bi*SEQ + (size_t)h*NSUB + ni) * D_IN;
  int lane = threadIdx.x;
  float acc[E_];
  #pragma unroll
  for (int e = 0; e < E_; ++e) acc[e] = 0.f;
  #pragma unroll
  for (int it = 0; it < D_IN/256; ++it) {
    f32x4 xv = *(const f32x4*)(xr + it*256 + lane*4);
    #pragma unroll
    for (int j = 0; j < 4; ++j) {
      float xs = xv[j];
      const float* wrow = Wg + (size_t)(it*256 + lane*4 + j) * E_;
      #pragma unroll
      for (int e = 0; e < E_; ++e) acc[e] += xs * wrow[e];
    }
  }
  #pragma unroll
  for (int e = 0; e < E_; ++e) {
    float v = acc[e];
    v += __shfl_xor(v, 32); v += __shfl_xor(v, 16); v += __shfl_xor(v, 8);
    v += __shfl_xor(v, 4);  v += __shfl_xor(v, 2);  v += __shfl_xor(v, 1);
    acc[e] = v;
  }
  if (lane == 0) {
    float mx = acc[0];
    #pragma unroll
    for (int e = 1; e < E_; ++e) mx = fmaxf(mx, acc[e]);
    float den = 0.f;
    #pragma unroll
    for (int e = 0; e < E_; ++e) den += expf(acc[e] - mx);
    int i1 = 0; float v1 = acc[0];
    #pragma unroll
    for (int e = 1; e < E_; ++e) if (acc[e] > v1) { v1 = acc[e]; i1 = e; }  // first max
    int i2 = -1; float v2 = -3.4e38f;
    #pragma unroll
    for (int e = 0; e < E_; ++e) if (e != i1 && acc[e] > v2) { v2 = acc[e]; i2 = e; }
    tokE1[tg] = i1; tokE2[tg] = i2;
    tokG1[tg] = expf(v1 - mx) / den;   // raw softmax probs; renorm after drops
    tokG2[tg] = expf(v2 - mx) / den;
  }
}

// ---- 2) slot map init ----------------------------------------------------
__global__ void k_init_slots(int* __restrict__ slotTok) {
  slotTok[blockIdx.x*256 + threadIdx.x] = -1;
}

// ---- 3) capacity scan: exact cumsum order, loc2 offset by RAW top1 totals
__global__ __launch_bounds__(64)
void k_scan(const int* __restrict__ tokE1, const int* __restrict__ tokE2,
            float* __restrict__ tokG1, float* __restrict__ tokG2,
            int* __restrict__ tokP1, int* __restrict__ tokP2,
            int* __restrict__ slotTok) {
  int h = blockIdx.x;
  int lane = threadIdx.x;
  __shared__ int cnt[64][E_];
  __shared__ int tot1[E_];
  const int CH = S_/64;                           // 32 tokens per lane chunk
  const int* e1 = tokE1 + h*S_;
  const int* e2 = tokE2 + h*S_;
  // choice 1
  #pragma unroll
  for (int e = 0; e < E_; ++e) cnt[lane][e] = 0;
  __syncthreads();
  for (int k = 0; k < CH; ++k) cnt[lane][e1[lane*CH + k]]++;
  __syncthreads();
  if (lane < E_) {
    int run = 0;
    for (int j = 0; j < 64; ++j) { int t = cnt[j][lane]; cnt[j][lane] = run; run += t; }
    tot1[lane] = run;                             // raw (pre-capacity) total
  }
  __syncthreads();
  for (int k = 0; k < CH; ++k) {
    int s = lane*CH + k;
    int e = e1[s];
    int p = cnt[lane][e]++;
    int tg = h*S_ + s;
    if (p < CAP) { tokP1[tg] = p; slotTok[e*MR + h*CAP + p] = tg; }
    else         { tokP1[tg] = -1; }
  }
  __syncthreads();
  // choice 2 (offset by raw tot1)
  #pragma unroll
  for (int e = 0; e < E_; ++e) cnt[lane][e] = 0;
  __syncthreads();
  for (int k = 0; k < CH; ++k) cnt[lane][e2[lane*CH + k]]++;
  __syncthreads();
  if (lane < E_) {
    int run = tot1[lane];
    for (int j = 0; j < 64; ++j) { int t = cnt[j][lane]; cnt[j][lane] = run; run += t; }
  }
  __syncthreads();
  for (int k = 0; k < CH; ++k) {
    int s = lane*CH + k;
    int e = e2[s];
    int p = cnt[lane][e]++;
    int tg = h*S_ + s;
    if (p < CAP) { tokP2[tg] = p; slotTok[e*MR + h*CAP + p] = tg; }
    else         { tokP2[tg] = -1; }
  }
  __syncthreads();
  // gate renorm after capacity drops (den cancels softmax norm exactly)
  for (int k = 0; k < CH; ++k) {
    int tg = h*S_ + k*64 + lane;
    float g1 = (tokP1[tg] >= 0) ? tokG1[tg] : 0.f;
    float g2 = (tokP2[tg] >= 0) ? tokG2[tg] : 0.f;
    float den = fmaxf(g1 + g2, 1e-9f);
    tokG1[tg] = g1 / den;
    tokG2[tg] = g2 / den;
  }
}

// ---- 4) gather tokens -> A1 bf16 [E][MR][D_IN], XOR swizzle baked --------
__global__ __launch_bounds__(256)
void k_gather1(const float* __restrict__ x, const int* __restrict__ slotTok,
               unsigned short* __restrict__ A1) {
  int row = blockIdx.x;                // e*MR + r ; row&7 == r&7 (MR%8==0)
  int tok = slotTok[row];
  int t = threadIdx.x;
  int k = t*4;
  int ba = ((k & 63)*2) ^ ((row & 7) << 4);       // swizzle within 64-elem chunk
  char* dst = (char*)A1 + (size_t)row*(D_IN*2) + (size_t)(k >> 6)*128 + ba;
  u16x4 pk;
  if (tok >= 0) {
    int h = tok >> 11, s = tok & 2047;
    int bi = s >> 9, ni = s & 511;
    const float* xr = x + ((size_t)bi*SEQ + (size_t)h*NSUB + ni) * D_IN;
    f32x4 v = *(const f32x4*)(xr + k);
    pk.x = f2bf(v.x); pk.y = f2bf(v.y); pk.z = f2bf(v.z); pk.w = f2bf(v.w);
  } else {
    pk.x = 0; pk.y = 0; pk.z = 0; pk.w = 0;
  }
  *(u16x4*)dst = pk;
}

// ---- 4b) W fp32 [E][K][N] -> Wt bf16 [E][N][K] transposed, swizzle baked -
// Lane-contiguous loads (16 lanes cover one row's 256B), LDS transpose,
// coalesced 128B-per-row swizzled stores.
template<int K, int N>
__global__ __launch_bounds__(256)
void k_cvtW(const float* __restrict__ W, unsigned short* __restrict__ Wt) {
  const int NB = N/64, KB = K/64;
  int bid = blockIdx.x;
  int kb = bid % KB;
  int rem = bid / KB;
  int nb = rem % NB;
  int e  = rem / NB;
  __shared__ float lds[64][65];
  int t = threadIdx.x;
  // load: pass p covers rows p*16..p*16+15; lane-contiguous 16B chunks
  int rl = t >> 4;              // 0..15
  int cl = (t & 15) * 4;        // 0..60
  const float* base = W + ((size_t)e*K + (size_t)kb*64)*N + (size_t)nb*64;
  #pragma unroll
  for (int p = 0; p < 4; ++p) {
    int r = p*16 + rl;
    f32x4 v = *(const f32x4*)(base + (size_t)r*N + cl);
    lds[cl+0][r] = v.x; lds[cl+1][r] = v.y; lds[cl+2][r] = v.z; lds[cl+3][r] = v.w;
  }
  __syncthreads();
  // store: row n = t>>2, 32 k-elems per thread as 2 swizzled u16x8
  int nl = t >> 2, kg = (t & 3) * 16;
  u16x8 c0, c1;
  #pragma unroll
  for (int j = 0; j < 8; ++j) {
    c0[j] = f2bf(lds[nl][kg + j]);
    c1[j] = f2bf(lds[nl][kg + 8 + j]);
  }
  char* dst = (char*)Wt + ((size_t)e*N + (size_t)nb*64 + nl)*(K*2) + (size_t)kb*128;
  int sw = (nl & 7) << 4;
  *(u16x8*)(dst + ((kg*2)      ^ sw)) = c0;
  *(u16x8*)(dst + ((kg*2 + 16) ^ sw)) = c1;
}

// ---- 5) GEMM: Out[e](+kc partial) = A[e] @ Wt[e]^T + bias[e]
// 256x256 tile, BK=64, 8 waves, wave tile 128x64, mfma 16x16x32 bf16.
// T3/T4: stage-insts for tile t+1 spread over the 4 phases of tile t
// (ph1:B01 ph2:B23 ph3:A02 ph4:A13); counted vmcnt(2) — never drain to 0.
// Consumption map (why vmcnt(2) is safe): ph1 reads B0-3 + A0,A2 (issued
// >=2 phases earlier, covered by tile-end vmcnt(2)+barrier); ph2 reads
// A1,A3 (issued ph4 prev tile, covered by ph1's vmcnt(2)+barrier). Each
// wave waits its own vmcnt BEFORE the barrier, so the barrier certifies
// all waves' loads arrived (gload_lds chunks are cross-wave).
template<int KROW, int KCHUNK, int N>
__global__ __launch_bounds__(512, 2)
void k_gemm(const unsigned short* __restrict__ A, const unsigned short* __restrict__ Wt,
            const float* __restrict__ bias, unsigned short* __restrict__ Out) {
  const int NT = N / 256;
  const int KSPLIT = KROW / KCHUNK;
  const int NKT = KCHUNK / 64;          // 16
  int cpx = gridDim.x >> 3;             // gridDim % 8 == 0
  int lb = blockIdx.x;
  int bid = (lb & 7) * cpx + (lb >> 3); // XCD-bijective swizzle
  int mt  = bid % MTILE;                // mt innermost: 3 blocks share W panel
  int rem = bid / MTILE;
  int kc  = rem % KSPLIT;
  rem /= KSPLIT;
  int nt  = rem % NT;
  int e   = rem / NT;

  const char* Ab = (const char*)A  + ((size_t)e*MR + (size_t)mt*256) * (KROW*2);
  const char* Bb = (const char*)Wt + ((size_t)e*N  + (size_t)nt*256) * (KROW*2);
  size_t kbase = (size_t)kc * (KCHUNK*2);

  __shared__ unsigned short As0[256*64];   // 32 KB each
  __shared__ unsigned short As1[256*64];
  __shared__ unsigned short Bs0[256*64];
  __shared__ unsigned short Bs1[256*64];

  int tid  = threadIdx.x;
  int lane = tid & 63;
  int wid  = tid >> 6;
  int wr = wid >> 2, wc = wid & 3;        // wave -> 128(M) x 64(N) sub-tile

  f32x4 acc[8][4];
  #pragma unroll
  for (int i = 0; i < 8; ++i)
    #pragma unroll
    for (int j = 0; j < 4; ++j) acc[i][j] = (f32x4)0.f;

  auto stageAi = [&](int kt2, unsigned short* As, int i) {  // rows i*64..+63
    size_t koff = kbase + (size_t)kt2*128;
    int L = i*8192 + tid*16;
    __builtin_amdgcn_global_load_lds(
        (const __attribute__((address_space(1))) void*)(Ab + (size_t)(L >> 7)*(KROW*2) + koff + (L & 127)),
        (__attribute__((address_space(3))) void*)((char*)As + L), 16, 0, 0);
  };
  auto stageBi = [&](int kt2, unsigned short* Bs, int i) {  // cols i*64..+63
    size_t koff = kbase + (size_t)kt2*128;
    int L = i*8192 + tid*16;
    __builtin_amdgcn_global_load_lds(
        (const __attribute__((address_space(1))) void*)(Bb + (size_t)(L >> 7)*(KROW*2) + koff + (L & 127)),
        (__attribute__((address_space(3))) void*)((char*)Bs + L), 16, 0, 0);
  };
  auto fragsA = [&](const unsigned short* As, int ra, int ks, s16x8* afr) {
    int kb = ks*64 + (lane >> 4)*16;
    #pragma unroll
    for (int i = 0; i < 4; ++i) {
      int r = wr*128 + ra*64 + i*16 + (lane & 15);
      afr[i] = *(const s16x8*)((const char*)As + r*128 + (kb ^ ((r & 7) << 4)));
    }
  };
  auto fragsB = [&](const unsigned short* Bs, int ks, s16x8* bfr) {
    int kb = ks*64 + (lane >> 4)*16;
    #pragma unroll
    for (int j = 0; j < 4; ++j) {
      int c = wc*64 + j*16 + (lane & 15);
      bfr[j] = *(const s16x8*)((const char*)Bs + c*128 + (kb ^ ((c & 7) << 4)));
    }
  };
  auto mfma16 = [&](int ra, const s16x8* afr, const s16x8* bfr) {
    __builtin_amdgcn_s_setprio(1);
    #pragma unroll
    for (int i = 0; i < 4; ++i)
      #pragma unroll
      for (int j = 0; j < 4; ++j)
        acc[ra*4+i][j] = __builtin_amdgcn_mfma_f32_16x16x32_bf16(afr[i], bfr[j], acc[ra*4+i][j], 0, 0, 0);
    __builtin_amdgcn_s_setprio(0);
  };

  unsigned short *Acur = As0, *Anxt = As1, *Bcur = Bs0, *Bnxt = Bs1;

  // prologue: stage tile 0 in steady-state issue order; leave A1,A3 in flight
  stageBi(0, Bcur, 0); stageBi(0, Bcur, 1); stageBi(0, Bcur, 2); stageBi(0, Bcur, 3);
  stageAi(0, Acur, 0); stageAi(0, Acur, 2);
  stageAi(0, Acur, 1); stageAi(0, Acur, 3);
  asm volatile("s_waitcnt vmcnt(2)" ::: "memory");
  __builtin_amdgcn_sched_barrier(0);
  __builtin_amdgcn_s_barrier();

  for (int kt = 0; kt < NKT; ++kt) {
    int tn = (kt + 1 < NKT) ? kt + 1 : kt;   // clamped dup stage on last tile
    s16x8 afr[4], bfr[4];
    // ---- ph1: needs B0-3,A0,A2 (arrived); A1,A3 still in flight ----------
    fragsA(Acur, 0, 0, afr); fragsB(Bcur, 0, bfr);
    stageBi(tn, Bnxt, 0); stageBi(tn, Bnxt, 1);
    asm volatile("s_waitcnt vmcnt(2)" ::: "memory");   // A1,A3(cur) done
    __builtin_amdgcn_sched_barrier(0);
    __builtin_amdgcn_s_barrier();
    asm volatile("s_waitcnt lgkmcnt(0)" ::: "memory");
    __builtin_amdgcn_sched_barrier(0);
    mfma16(0, afr, bfr);
    __builtin_amdgcn_s_barrier();
    // ---- ph2: reads A1,A3 regions (certified by ph1 vmcnt+barrier) -------
    fragsA(Acur, 1, 0, afr);
    stageBi(tn, Bnxt, 2); stageBi(tn, Bnxt, 3);
    __builtin_amdgcn_s_barrier();
    asm volatile("s_waitcnt lgkmcnt(0)" ::: "memory");
    __builtin_amdgcn_sched_barrier(0);
    mfma16(1, afr, bfr);
    __builtin_amdgcn_s_barrier();
    // ---- ph3 -------------------------------------------------------------
    fragsA(Acur, 0, 1, afr); fragsB(Bcur, 1, bfr);
    stageAi(tn, Anxt, 0); stageAi(tn, Anxt, 2);
    __builtin_amdgcn_s_barrier();
    asm volatile("s_waitcnt lgkmcnt(0)" ::: "memory");
    __builtin_amdgcn_sched_barrier(0);
    mfma16(0, afr, bfr);
    __builtin_amdgcn_s_barrier();
    // ---- ph4 -------------------------------------------------------------
    fragsA(Acur, 1, 1, afr);
    stageAi(tn, Anxt, 1); stageAi(tn, Anxt, 3);
    __builtin_amdgcn_s_barrier();
    asm volatile("s_waitcnt lgkmcnt(0)" ::: "memory");
    __builtin_amdgcn_sched_barrier(0);
    mfma16(1, afr, bfr);
    // tile-end: wait B0-3,A0,A2 of next (leaves A1,A3 flying); barrier
    asm volatile("s_waitcnt vmcnt(2)" ::: "memory");
    __builtin_amdgcn_sched_barrier(0);
    __builtin_amdgcn_s_barrier();
    unsigned short* t1 = Acur; Acur = Anxt; Anxt = t1;
    unsigned short* t2 = Bcur; Bcur = Bnxt; Bnxt = t2;
  }

  // epilogue: +bias (only kc==0), bf16 store (plain layout, partial kc)
  unsigned short* Op = Out + (size_t)kc * ((size_t)E_*MR*N);
  #pragma unroll
  for (int j = 0; j < 4; ++j) {
    int col = nt*256 + wc*64 + j*16 + (lane & 15);
    float bv = (kc == 0) ? bias[(size_t)e*N + col] : 0.f;
    #pragma unroll
    for (int i = 0; i < 8; ++i) {
      int rowb = mt*256 + wr*128 + i*16 + (lane >> 4)*4;
      #pragma unroll
      for (int r = 0; r < 4; ++r) {
        float v = acc[i][j][r] + bv;
        Op[(size_t)e*MR*N + (size_t)(rowb + r)*N + col] = f2bf(v);
      }
    }
  }
}

// ---- 6) zero A2 rows with no token (incl. pad rows) ----------------------
__global__ __launch_bounds__(256)
void k_zero_empty(const int* __restrict__ slotTok, unsigned short* __restrict__ A2) {
  int row = blockIdx.x;
  if (slotTok[row] >= 0) return;
  u32x4 z = (u32x4)0u;
  char* base = (char*)A2 + (size_t)row*(D_HID*2) + threadIdx.x*32;
  *(u32x4*)base = z;
  *(u32x4*)(base + 16) = z;
}

// ---- 7) combine g1*H1[r1]+g2*H1[r2] -> LN -> ReLU -> redispatch into A2 --
__global__ __launch_bounds__(256)
void k_combine_ln(const unsigned short* __restrict__ H1,
                  const int* __restrict__ tokE1, const int* __restrict__ tokE2,
                  const int* __restrict__ tokP1, const int* __restrict__ tokP2,
                  const float* __restrict__ tokG1, const float* __restrict__ tokG2,
                  const float* __restrict__ lnw, const float* __restrict__ lnb,
                  unsigned short* __restrict__ A2) {
  int tg = blockIdx.x;
  int h = tg >> 11;
  int p1 = tokP1[tg], p2 = tokP2[tg];
  if (p1 < 0 && p2 < 0) return;                       // no slots; rows zeroed
  float g1 = tokG1[tg], g2 = tokG2[tg];
  long r1 = (p1 >= 0) ? ((long)tokE1[tg]*MR + h*CAP + p1) : -1;
  long r2 = (p2 >= 0) ? ((long)tokE2[tg]*MR + h*CAP + p2) : -1;
  int t = threadIdx.x;
  float v[16];
  float sum = 0.f, sq = 0.f;
  #pragma unroll
  for (int u = 0; u < 4; ++u) {
    int f = u*1024 + t*4;
    float a0 = 0.f, a1 = 0.f, a2 = 0.f, a3 = 0.f;
    if (r1 >= 0) {
      u16x4 q = *(const u16x4*)(H1 + (size_t)r1*D_HID + f);
      a0 += g1*bf2f(q.x); a1 += g1*bf2f(q.y); a2 += g1*bf2f(q.z); a3 += g1*bf2f(q.w);
    }
    if (r2 >= 0) {
      u16x4 q = *(const u16x4*)(H1 + (size_t)r2*D_HID + f);
      a0 += g2*bf2f(q.x); a1 += g2*bf2f(q.y); a2 += g2*bf2f(q.z); a3 += g2*bf2f(q.w);
    }
    v[u*4+0] = a0; v[u*4+1] = a1; v[u*4+2] = a2; v[u*4+3] = a3;
    sum += a0 + a1 + a2 + a3;
    sq  += a0*a0 + a1*a1 + a2*a2 + a3*a3;
  }
  #pragma unroll
  for (int o = 32; o; o >>= 1) { sum += __shfl_xor(sum, o); sq += __shfl_xor(sq, o); }
  __shared__ float redA[4], redB[4];
  int wid = t >> 6;
  if ((t & 63) == 0) { redA[wid] = sum; redB[wid] = sq; }
  __syncthreads();
  float S = redA[0] + redA[1] + redA[2] + redA[3];
  float Q = redB[0] + redB[1] + redB[2] + redB[3];
  float m = S * (1.f / D_HID);
  float var = Q * (1.f / D_HID) - m*m;
  float rs = rsqrtf(var + 1e-6f);
  #pragma unroll
  for (int u = 0; u < 4; ++u) {
    int f = u*1024 + t*4;
    u16x4 pk;
    float y0 = fmaxf((v[u*4+0]-m)*rs*lnw[h*D_HID+f+0] + lnb[h*D_HID+f+0], 0.f);
    float y1 = fmaxf((v[u*4+1]-m)*rs*lnw[h*D_HID+f+1] + lnb[h*D_HID+f+1], 0.f);
    float y2 = fmaxf((v[u*4+2]-m)*rs*lnw[h*D_HID+f+2] + lnb[h*D_HID+f+2], 0.f);
    float y3 = fmaxf((v[u*4+3]-m)*rs*lnw[h*D_HID+f+3] + lnb[h*D_HID+f+3], 0.f);
    pk.x = f2bf(y0); pk.y = f2bf(y1); pk.z = f2bf(y2); pk.w = f2bf(y3);
    int chunk = f >> 6;
    int ob = (f & 63)*2;
    if (r1 >= 0)
      *(u16x4*)((char*)A2 + (size_t)r1*(D_HID*2) + (size_t)chunk*128 + (ob ^ (((int)r1 & 7) << 4))) = pk;
    if (r2 >= 0)
      *(u16x4*)((char*)A2 + (size_t)r2*(D_HID*2) + (size_t)chunk*128 + (ob ^ (((int)r2 & 7) << 4))) = pk;
  }
}

// ---- 8) final: sum 4 GEMM2 partials + residual + LayerNorm ---------------
__global__ __launch_bounds__(256)
void k_final(const unsigned short* __restrict__ H2p, const float* __restrict__ x,
             const int* __restrict__ tokE1, const int* __restrict__ tokE2,
             const int* __restrict__ tokP1, const int* __restrict__ tokP2,
             const float* __restrict__ tokG1, const float* __restrict__ tokG2,
             const float* __restrict__ lnw, const float* __restrict__ lnb,
             float* __restrict__ out) {
  const size_t PSTR = (size_t)E_*MR*D_IN;
  int tg = blockIdx.x;
  int h = tg >> 11, s = tg & 2047;
  int bi = s >> 9, ni = s & 511;
  size_t xoff = ((size_t)bi*SEQ + (size_t)h*NSUB + ni) * D_IN;
  int p1 = tokP1[tg], p2 = tokP2[tg];
  float g1 = tokG1[tg], g2 = tokG2[tg];
  int t = threadIdx.x;
  int f = t*4;
  f32x4 xv = *(const f32x4*)(x + xoff + f);
  float v0 = xv.x, v1 = xv.y, v2 = xv.z, v3 = xv.w;
  if (p1 >= 0) {
    size_t r1 = (size_t)tokE1[tg]*MR + h*CAP + p1;
    float a0 = 0.f, a1 = 0.f, a2 = 0.f, a3 = 0.f;
    #pragma unroll
    for (int p = 0; p < KSPL2; ++p) {
      u16x4 q = *(const u16x4*)(H2p + p*PSTR + r1*D_IN + f);
      a0 += bf2f(q.x); a1 += bf2f(q.y); a2 += bf2f(q.z); a3 += bf2f(q.w);
    }
    v0 += g1*a0; v1 += g1*a1; v2 += g1*a2; v3 += g1*a3;
  }
  if (p2 >= 0) {
    size_t r2 = (size_t)tokE2[tg]*MR + h*CAP + p2;
    float a0 = 0.f, a1 = 0.f, a2 = 0.f, a3 = 0.f;
    #pragma unroll
    for (int p = 0; p < KSPL2; ++p) {
      u16x4 q = *(const u16x4*)(H2p + p*PSTR + r2*D_IN + f);
      a0 += bf2f(q.x); a1 += bf2f(q.y); a2 += bf2f(q.z); a3 += bf2f(q.w);
    }
    v0 += g2*a0; v1 += g2*a1; v2 += g2*a2; v3 += g2*a3;
  }
  float sum = v0+v1+v2+v3, sq = v0*v0+v1*v1+v2*v2+v3*v3;
  #pragma unroll
  for (int o = 32; o; o >>= 1) { sum += __shfl_xor(sum, o); sq += __shfl_xor(sq, o); }
  __shared__ float redA[4], redB[4];
  int wid = t >> 6;
  if ((t & 63) == 0) { redA[wid] = sum; redB[wid] = sq; }
  __syncthreads();
  float S = redA[0] + redA[1] + redA[2] + redA[3];
  float Q = redB[0] + redB[1] + redB[2] + redB[3];
  float m = S * (1.f / D_IN);
  float var = Q * (1.f / D_IN) - m*m;
  float rs = rsqrtf(var + 1e-6f);
  f32x4 res;
  res.x = (v0 - m)*rs*lnw[f+0] + lnb[f+0];
  res.y = (v1 - m)*rs*lnw[f+1] + lnb[f+1];
  res.z = (v2 - m)*rs*lnw[f+2] + lnb[f+2];
  res.w = (v3 - m)*rs*lnw[f+3] + lnb[f+3];
  *(f32x4*)(out + xoff + f) = res;
}

// ---- launcher ------------------------------------------------------------
extern "C" void kernel_launch(void* const* d_in, const int* in_sizes, int n_in,
                              void* d_out, int out_size, void* d_ws, size_t ws_size,
                              hipStream_t stream) {
  const float* x    = (const float*)d_in[0];
  const float* Wg   = (const float*)d_in[1];
  const float* W1   = (const float*)d_in[2];
  const float* b1   = (const float*)d_in[3];
  const float* W2   = (const float*)d_in[4];
  const float* b2   = (const float*)d_in[5];
  const float* lnhw = (const float*)d_in[6];
  const float* lnhb = (const float*)d_in[7];
  const float* lnow = (const float*)d_in[8];
  const float* lnob = (const float*)d_in[9];
  float* out = (float*)d_out;
  (void)in_sizes; (void)n_in; (void)out_size; (void)ws_size;

  char* ws = (char*)d_ws;
  size_t off = 0;
  auto take = [&](size_t bytes) -> char* {
    char* p = ws + off;
    off += (bytes + 255) & ~(size_t)255;
    return p;
  };
  int*   tokE1 = (int*)take(NTOKG*sizeof(int));
  int*   tokE2 = (int*)take(NTOKG*sizeof(int));
  int*   tokP1 = (int*)take(NTOKG*sizeof(int));
  int*   tokP2 = (int*)take(NTOKG*sizeof(int));
  float* tokG1 = (float*)take(NTOKG*sizeof(float));
  float* tokG2 = (float*)take(NTOKG*sizeof(float));
  int*   slotTok = (int*)take((size_t)E_*MR*sizeof(int));
  unsigned short* A1 = (unsigned short*)take((size_t)E_*MR*D_IN*2);   //  37.7 MB
  unsigned short* H1 = (unsigned short*)take((size_t)E_*MR*D_HID*2);  // 151 MB (= 4x GEMM2 partials)
  unsigned short* A2 = (unsigned short*)take((size_t)E_*MR*D_HID*2);  // 151 MB
  unsigned short* Wt = (unsigned short*)take((size_t)E_*D_IN*D_HID*2);// 201 MB (shared W1t/W2t)
  unsigned short* H2p = H1;   // GEMM2 partials alias dead H1 (after combine_ln)

  k_init_slots<<<dim3(E_*MR/256), dim3(256), 0, stream>>>(slotTok);
  k_gating<<<dim3(NTOKG), dim3(64), 0, stream>>>(x, Wg, tokE1, tokE2, tokG1, tokG2);
  k_scan<<<dim3(HGRP), dim3(64), 0, stream>>>(tokE1, tokE2, tokG1, tokG2, tokP1, tokP2, slotTok);
  k_gather1<<<dim3(E_*MR), dim3(256), 0, stream>>>(x, slotTok, A1);
  k_cvtW<D_IN, D_HID><<<dim3(E_*(D_HID/64)*(D_IN/64)), dim3(256), 0, stream>>>(W1, Wt);
  k_gemm<D_IN, D_IN, D_HID><<<dim3(E_*(D_HID/256)*MTILE), dim3(512), 0, stream>>>(A1, Wt, b1, H1);
  k_zero_empty<<<dim3(E_*MR), dim3(256), 0, stream>>>(slotTok, A2);
  k_combine_ln<<<dim3(NTOKG), dim3(256), 0, stream>>>(H1, tokE1, tokE2, tokP1, tokP2,
                                                      tokG1, tokG2, lnhw, lnhb, A2);
  k_cvtW<D_HID, D_IN><<<dim3(E_*(D_IN/64)*(D_HID/64)), dim3(256), 0, stream>>>(W2, Wt);
  k_gemm<D_HID, D_IN, D_IN><<<dim3(E_*(D_IN/256)*MTILE*KSPL2), dim3(512), 0, stream>>>(A2, Wt, b2, H2p);
  k_final<<<dim3(NTOKG), dim3(256), 0, stream>>>(H2p, x, tokE1, tokE2, tokP1, tokP2,
                                                 tokG1, tokG2, lnow, lnob, out);
}

// Round 7
// 862.424 us; speedup vs baseline: 1.0413x; 1.0151x over previous
//
#include <hip/hip_runtime.h>
#include <cstdint>
#include <cstddef>

// ---- fixed problem shape (from setup_inputs) ------------------------------
#define E_      24          // experts
#define D_IN    1024
#define D_HID   4096
#define HGRP    4           // groups (H)
#define BSZ     4
#define SEQ     2048
#define NSUB    512         // seq / HGRP
#define S_      2048        // tokens per group = BSZ*NSUB
#define NTOKG   8192        // HGRP * S_
#define CAP     171         // ceil(2*S_/E_)
#define MR      768         // per-expert rows, 4*CAP=684 padded to 3*256
#define MTILE   3           // M tiles of 256
#define KSPL2   4           // GEMM2 K-split (chunks of 1024)

typedef __attribute__((ext_vector_type(4))) float          f32x4;
typedef __attribute__((ext_vector_type(4))) unsigned short u16x4;
typedef __attribute__((ext_vector_type(8))) unsigned short u16x8;
typedef __attribute__((ext_vector_type(4))) unsigned int   u32x4;
typedef __attribute__((ext_vector_type(8))) short          s16x8;

__device__ __forceinline__ unsigned short f2bf(float f) {   // RNE f32->bf16
  unsigned int u = __float_as_uint(f);
  u += 0x7fffu + ((u >> 16) & 1u);
  return (unsigned short)(u >> 16);
}
__device__ __forceinline__ float bf2f(unsigned short v) {
  return __uint_as_float(((unsigned int)v) << 16);
}

// ---- 1) gating: logits = x_row @ Wg, softmax, top-2 (first-max ties) -----
__global__ __launch_bounds__(64)
void k_gating(const float* __restrict__ x, const float* __restrict__ Wg,
              int* __restrict__ tokE1, int* __restrict__ tokE2,
              float* __restrict__ tokG1, float* __restrict__ tokG2) {
  int tg = blockIdx.x;                 // h*S_ + s
  int h = tg >> 11, s = tg & 2047;
  int bi = s >> 9, ni = s & 511;
  const float* xr = x + ((size_t)bi*SEQ + (size_t)h*NSUB + ni) * D_IN;
  int lane = threadIdx.x;
  float acc[E_];
  #pragma unroll
  for (int e = 0; e < E_; ++e) acc[e] = 0.f;
  #pragma unroll
  for (int it = 0; it < D_IN/256; ++it) {
    f32x4 xv = *(const f32x4*)(xr + it*256 + lane*4);
    #pragma unroll
    for (int j = 0; j < 4; ++j) {
      float xs = xv[j];
      const float* wrow = Wg + (size_t)(it*256 + lane*4 + j) * E_;
      #pragma unroll
      for (int e = 0; e < E_; ++e) acc[e] += xs * wrow[e];
    }
  }
  #pragma unroll
  for (int e = 0; e < E_; ++e) {
    float v = acc[e];
    v += __shfl_xor(v, 32); v += __shfl_xor(v, 16); v += __shfl_xor(v, 8);
    v += __shfl_xor(v, 4);  v += __shfl_xor(v, 2);  v += __shfl_xor(v, 1);
    acc[e] = v;
  }
  if (lane == 0) {
    float mx = acc[0];
    #pragma unroll
    for (int e = 1; e < E_; ++e) mx = fmaxf(mx, acc[e]);
    float den = 0.f;
    #pragma unroll
    for (int e = 0; e < E_; ++e) den += expf(acc[e] - mx);
    int i1 = 0; float v1 = acc[0];
    #pragma unroll
    for (int e = 1; e < E_; ++e) if (acc[e] > v1) { v1 = acc[e]; i1 = e; }  // first max
    int i2 = -1; float v2 = -3.4e38f;
    #pragma unroll
    for (int e = 0; e < E_; ++e) if (e != i1 && acc[e] > v2) { v2 = acc[e]; i2 = e; }
    tokE1[tg] = i1; tokE2[tg] = i2;
    tokG1[tg] = expf(v1 - mx) / den;   // raw softmax probs; renorm after drops
    tokG2[tg] = expf(v2 - mx) / den;
  }
}

// ---- 2) slot map init ----------------------------------------------------
__global__ void k_init_slots(int* __restrict__ slotTok) {
  slotTok[blockIdx.x*256 + threadIdx.x] = -1;
}

// ---- 3) capacity scan: exact cumsum order, loc2 offset by RAW top1 totals
__global__ __launch_bounds__(64)
void k_scan(const int* __restrict__ tokE1, const int* __restrict__ tokE2,
            float* __restrict__ tokG1, float* __restrict__ tokG2,
            int* __restrict__ tokP1, int* __restrict__ tokP2,
            int* __restrict__ slotTok) {
  int h = blockIdx.x;
  int lane = threadIdx.x;
  __shared__ int cnt[64][E_];
  __shared__ int tot1[E_];
  const int CH = S_/64;                           // 32 tokens per lane chunk
  const int* e1 = tokE1 + h*S_;
  const int* e2 = tokE2 + h*S_;
  // choice 1
  #pragma unroll
  for (int e = 0; e < E_; ++e) cnt[lane][e] = 0;
  __syncthreads();
  for (int k = 0; k < CH; ++k) cnt[lane][e1[lane*CH + k]]++;
  __syncthreads();
  if (lane < E_) {
    int run = 0;
    for (int j = 0; j < 64; ++j) { int t = cnt[j][lane]; cnt[j][lane] = run; run += t; }
    tot1[lane] = run;                             // raw (pre-capacity) total
  }
  __syncthreads();
  for (int k = 0; k < CH; ++k) {
    int s = lane*CH + k;
    int e = e1[s];
    int p = cnt[lane][e]++;
    int tg = h*S_ + s;
    if (p < CAP) { tokP1[tg] = p; slotTok[e*MR + h*CAP + p] = tg; }
    else         { tokP1[tg] = -1; }
  }
  __syncthreads();
  // choice 2 (offset by raw tot1)
  #pragma unroll
  for (int e = 0; e < E_; ++e) cnt[lane][e] = 0;
  __syncthreads();
  for (int k = 0; k < CH; ++k) cnt[lane][e2[lane*CH + k]]++;
  __syncthreads();
  if (lane < E_) {
    int run = tot1[lane];
    for (int j = 0; j < 64; ++j) { int t = cnt[j][lane]; cnt[j][lane] = run; run += t; }
  }
  __syncthreads();
  for (int k = 0; k < CH; ++k) {
    int s = lane*CH + k;
    int e = e2[s];
    int p = cnt[lane][e]++;
    int tg = h*S_ + s;
    if (p < CAP) { tokP2[tg] = p; slotTok[e*MR + h*CAP + p] = tg; }
    else         { tokP2[tg] = -1; }
  }
  __syncthreads();
  // gate renorm after capacity drops (den cancels softmax norm exactly)
  for (int k = 0; k < CH; ++k) {
    int tg = h*S_ + k*64 + lane;
    float g1 = (tokP1[tg] >= 0) ? tokG1[tg] : 0.f;
    float g2 = (tokP2[tg] >= 0) ? tokG2[tg] : 0.f;
    float den = fmaxf(g1 + g2, 1e-9f);
    tokG1[tg] = g1 / den;
    tokG2[tg] = g2 / den;
  }
}

// ---- 4) gather tokens -> A1 bf16 [E][MR][D_IN], XOR swizzle baked --------
__global__ __launch_bounds__(256)
void k_gather1(const float* __restrict__ x, const int* __restrict__ slotTok,
               unsigned short* __restrict__ A1) {
  int row = blockIdx.x;                // e*MR + r ; row&7 == r&7 (MR%8==0)
  int tok = slotTok[row];
  int t = threadIdx.x;
  int k = t*4;
  int ba = ((k & 63)*2) ^ ((row & 7) << 4);       // swizzle within 64-elem chunk
  char* dst = (char*)A1 + (size_t)row*(D_IN*2) + (size_t)(k >> 6)*128 + ba;
  u16x4 pk;
  if (tok >= 0) {
    int h = tok >> 11, s = tok & 2047;
    int bi = s >> 9, ni = s & 511;
    const float* xr = x + ((size_t)bi*SEQ + (size_t)h*NSUB + ni) * D_IN;
    f32x4 v = *(const f32x4*)(xr + k);
    pk.x = f2bf(v.x); pk.y = f2bf(v.y); pk.z = f2bf(v.z); pk.w = f2bf(v.w);
  } else {
    pk.x = 0; pk.y = 0; pk.z = 0; pk.w = 0;
  }
  *(u16x4*)dst = pk;
}

// ---- 5) GEMM: Out[e](+kc partial) = A[e] @ W[e] + bias[e]
// 256x256 tile, BK=64, 8 waves, wave tile 128x64, mfma 16x16x32 bf16.
// A: bf16 pre-swizzled in global, staged via global_load_lds (ph2/ph3).
// B: fp32 W [K][N] read directly — 8x f32x4 coalesced reg loads issued at
// ph1 (T14 issue-early), cvt+4x ds_write_b128 transposed+swizzled at ph4
// (write-late) into the NEXT buffer. Compiler inserts the exact vmcnt for
// the cvt dependency; only the tile-end __syncthreads drains (all A-glds
// are >=2 phases old there). Counted-wait schedule per T3/T4.
template<int KROW, int KCHUNK, int N>
__global__ __launch_bounds__(512, 2)
void k_gemm(const unsigned short* __restrict__ A, const float* __restrict__ W,
            const float* __restrict__ bias, unsigned short* __restrict__ Out) {
  const int NT = N / 256;
  const int KSPLIT = KROW / KCHUNK;
  const int NKT = KCHUNK / 64;          // 16
  int cpx = gridDim.x >> 3;             // gridDim % 8 == 0
  int lb = blockIdx.x;
  int bid = (lb & 7) * cpx + (lb >> 3); // XCD-bijective swizzle
  int mt  = bid % MTILE;                // mt innermost: 3 blocks share W panel
  int rem = bid / MTILE;
  int kc  = rem % KSPLIT;
  rem /= KSPLIT;
  int nt  = rem % NT;
  int e   = rem / NT;

  const char*  Ab = (const char*)A + ((size_t)e*MR + (size_t)mt*256) * (KROW*2);
  const float* We = W + (size_t)e*KROW*N + (size_t)nt*256;
  size_t kbase = (size_t)kc * (KCHUNK*2);

  __shared__ unsigned short As0[256*64];   // 32 KB each
  __shared__ unsigned short As1[256*64];
  __shared__ unsigned short Bs0[256*64];
  __shared__ unsigned short Bs1[256*64];

  int tid  = threadIdx.x;
  int lane = tid & 63;
  int wid  = tid >> 6;
  int wr = wid >> 2, wc = wid & 3;        // wave -> 128(M) x 64(N) sub-tile

  f32x4 acc[8][4];
  #pragma unroll
  for (int i = 0; i < 8; ++i)
    #pragma unroll
    for (int j = 0; j < 4; ++j) acc[i][j] = (f32x4)0.f;

  // B reg staging: thread owns cols bn..bn+3, k-rows bk..bk+7 of the 256x64
  // B tile. Loads: 8 lanes per k-row cover 128B contiguous. Writes: each
  // ds_write_b128 inst covers 8 full 128B rows -> banks perfectly even.
  int bn = ((tid >> 3) & 63) * 4;
  int bk = (tid & 7) * 8;
  f32x4 wv[8];

  auto loadB = [&](int kt2) {
    const float* p = We + (size_t)((size_t)kc*KCHUNK + (size_t)kt2*64 + bk)*N + bn;
    #pragma unroll
    for (int q = 0; q < 8; ++q) wv[q] = *(const f32x4*)(p + (size_t)q*N);
  };
  auto writeB = [&](unsigned short* Bs) {
    #pragma unroll
    for (int c = 0; c < 4; ++c) {
      u16x8 col;
      #pragma unroll
      for (int q = 0; q < 8; ++q) col[q] = f2bf(wv[q][c]);
      int n = bn + c;
      *(u16x8*)((char*)Bs + n*128 + ((bk*2) ^ ((n & 7) << 4))) = col;
    }
  };
  auto stageAi = [&](int kt2, unsigned short* As, int i) {  // rows i*64..+63
    size_t koff = kbase + (size_t)kt2*128;
    int L = i*8192 + tid*16;
    __builtin_amdgcn_global_load_lds(
        (const __attribute__((address_space(1))) void*)(Ab + (size_t)(L >> 7)*(KROW*2) + koff + (L & 127)),
        (__attribute__((address_space(3))) void*)((char*)As + L), 16, 0, 0);
  };
  auto fragsA = [&](const unsigned short* As, int ra, int ks, s16x8* afr) {
    int kb = ks*64 + (lane >> 4)*16;
    #pragma unroll
    for (int i = 0; i < 4; ++i) {
      int r = wr*128 + ra*64 + i*16 + (lane & 15);
      afr[i] = *(const s16x8*)((const char*)As + r*128 + (kb ^ ((r & 7) << 4)));
    }
  };
  auto fragsB = [&](const unsigned short* Bs, int ks, s16x8* bfr) {
    int kb = ks*64 + (lane >> 4)*16;
    #pragma unroll
    for (int j = 0; j < 4; ++j) {
      int c = wc*64 + j*16 + (lane & 15);
      bfr[j] = *(const s16x8*)((const char*)Bs + c*128 + (kb ^ ((c & 7) << 4)));
    }
  };
  auto mfma16 = [&](int ra, const s16x8* afr, const s16x8* bfr) {
    __builtin_amdgcn_s_setprio(1);
    #pragma unroll
    for (int i = 0; i < 4; ++i)
      #pragma unroll
      for (int j = 0; j < 4; ++j)
        acc[ra*4+i][j] = __builtin_amdgcn_mfma_f32_16x16x32_bf16(afr[i], bfr[j], acc[ra*4+i][j], 0, 0, 0);
    __builtin_amdgcn_s_setprio(0);
  };

  unsigned short *Acur = As0, *Anxt = As1, *Bcur = Bs0, *Bnxt = Bs1;

  // prologue: stage tile 0 (A via glds; B via regs->LDS)
  stageAi(0, Acur, 0); stageAi(0, Acur, 1); stageAi(0, Acur, 2); stageAi(0, Acur, 3);
  loadB(0);
  writeB(Bcur);                 // compiler waits the vloads here
  __syncthreads();              // drains glds + ds_writes, barrier

  for (int kt = 0; kt < NKT; ++kt) {
    int tn = (kt + 1 < NKT) ? kt + 1 : kt;   // clamped dup stage on last tile
    s16x8 afr[4], bfr[4];
    // ---- ph1: issue B(t+1) reg loads early --------------------------------
    fragsA(Acur, 0, 0, afr); fragsB(Bcur, 0, bfr);
    loadB(tn);
    __builtin_amdgcn_s_barrier();
    asm volatile("s_waitcnt lgkmcnt(0)" ::: "memory");
    __builtin_amdgcn_sched_barrier(0);
    mfma16(0, afr, bfr);
    __builtin_amdgcn_s_barrier();
    // ---- ph2 ---------------------------------------------------------------
    fragsA(Acur, 1, 0, afr);
    stageAi(tn, Anxt, 0); stageAi(tn, Anxt, 2);
    __builtin_amdgcn_s_barrier();
    asm volatile("s_waitcnt lgkmcnt(0)" ::: "memory");
    __builtin_amdgcn_sched_barrier(0);
    mfma16(1, afr, bfr);
    __builtin_amdgcn_s_barrier();
    // ---- ph3 ---------------------------------------------------------------
    fragsA(Acur, 0, 1, afr); fragsB(Bcur, 1, bfr);
    stageAi(tn, Anxt, 1); stageAi(tn, Anxt, 3);
    __builtin_amdgcn_s_barrier();
    asm volatile("s_waitcnt lgkmcnt(0)" ::: "memory");
    __builtin_amdgcn_sched_barrier(0);
    mfma16(0, afr, bfr);
    __builtin_amdgcn_s_barrier();
    // ---- ph4: write B(t+1) late, then single tile-end drain ---------------
    fragsA(Acur, 1, 1, afr);
    __builtin_amdgcn_s_barrier();
    asm volatile("s_waitcnt lgkmcnt(0)" ::: "memory");
    __builtin_amdgcn_sched_barrier(0);
    mfma16(1, afr, bfr);
    writeB(Bnxt);               // cvt + 4 ds_write (auto vmcnt for vloads)
    __syncthreads();            // drains A-glds (>=2 phases old) + ds_writes
    unsigned short* t1 = Acur; Acur = Anxt; Anxt = t1;
    unsigned short* t2 = Bcur; Bcur = Bnxt; Bnxt = t2;
  }

  // epilogue: +bias (only kc==0), bf16 store (plain layout, partial kc)
  unsigned short* Op = Out + (size_t)kc * ((size_t)E_*MR*N);
  #pragma unroll
  for (int j = 0; j < 4; ++j) {
    int col = nt*256 + wc*64 + j*16 + (lane & 15);
    float bv = (kc == 0) ? bias[(size_t)e*N + col] : 0.f;
    #pragma unroll
    for (int i = 0; i < 8; ++i) {
      int rowb = mt*256 + wr*128 + i*16 + (lane >> 4)*4;
      #pragma unroll
      for (int r = 0; r < 4; ++r) {
        float v = acc[i][j][r] + bv;
        Op[(size_t)e*MR*N + (size_t)(rowb + r)*N + col] = f2bf(v);
      }
    }
  }
}

// ---- 6) zero A2 rows with no token (incl. pad rows) ----------------------
__global__ __launch_bounds__(256)
void k_zero_empty(const int* __restrict__ slotTok, unsigned short* __restrict__ A2) {
  int row = blockIdx.x;
  if (slotTok[row] >= 0) return;
  u32x4 z = (u32x4)0u;
  char* base = (char*)A2 + (size_t)row*(D_HID*2) + threadIdx.x*32;
  *(u32x4*)base = z;
  *(u32x4*)(base + 16) = z;
}

// ---- 7) combine g1*H1[r1]+g2*H1[r2] -> LN -> ReLU -> redispatch into A2 --
__global__ __launch_bounds__(256)
void k_combine_ln(const unsigned short* __restrict__ H1,
                  const int* __restrict__ tokE1, const int* __restrict__ tokE2,
                  const int* __restrict__ tokP1, const int* __restrict__ tokP2,
                  const float* __restrict__ tokG1, const float* __restrict__ tokG2,
                  const float* __restrict__ lnw, const float* __restrict__ lnb,
                  unsigned short* __restrict__ A2) {
  int tg = blockIdx.x;
  int h = tg >> 11;
  int p1 = tokP1[tg], p2 = tokP2[tg];
  if (p1 < 0 && p2 < 0) return;                       // no slots; rows zeroed
  float g1 = tokG1[tg], g2 = tokG2[tg];
  long r1 = (p1 >= 0) ? ((long)tokE1[tg]*MR + h*CAP + p1) : -1;
  long r2 = (p2 >= 0) ? ((long)tokE2[tg]*MR + h*CAP + p2) : -1;
  int t = threadIdx.x;
  float v[16];
  float sum = 0.f, sq = 0.f;
  #pragma unroll
  for (int u = 0; u < 4; ++u) {
    int f = u*1024 + t*4;
    float a0 = 0.f, a1 = 0.f, a2 = 0.f, a3 = 0.f;
    if (r1 >= 0) {
      u16x4 q = *(const u16x4*)(H1 + (size_t)r1*D_HID + f);
      a0 += g1*bf2f(q.x); a1 += g1*bf2f(q.y); a2 += g1*bf2f(q.z); a3 += g1*bf2f(q.w);
    }
    if (r2 >= 0) {
      u16x4 q = *(const u16x4*)(H1 + (size_t)r2*D_HID + f);
      a0 += g2*bf2f(q.x); a1 += g2*bf2f(q.y); a2 += g2*bf2f(q.z); a3 += g2*bf2f(q.w);
    }
    v[u*4+0] = a0; v[u*4+1] = a1; v[u*4+2] = a2; v[u*4+3] = a3;
    sum += a0 + a1 + a2 + a3;
    sq  += a0*a0 + a1*a1 + a2*a2 + a3*a3;
  }
  #pragma unroll
  for (int o = 32; o; o >>= 1) { sum += __shfl_xor(sum, o); sq += __shfl_xor(sq, o); }
  __shared__ float redA[4], redB[4];
  int wid = t >> 6;
  if ((t & 63) == 0) { redA[wid] = sum; redB[wid] = sq; }
  __syncthreads();
  float S = redA[0] + redA[1] + redA[2] + redA[3];
  float Q = redB[0] + redB[1] + redB[2] + redB[3];
  float m = S * (1.f / D_HID);
  float var = Q * (1.f / D_HID) - m*m;
  float rs = rsqrtf(var + 1e-6f);
  #pragma unroll
  for (int u = 0; u < 4; ++u) {
    int f = u*1024 + t*4;
    u16x4 pk;
    float y0 = fmaxf((v[u*4+0]-m)*rs*lnw[h*D_HID+f+0] + lnb[h*D_HID+f+0], 0.f);
    float y1 = fmaxf((v[u*4+1]-m)*rs*lnw[h*D_HID+f+1] + lnb[h*D_HID+f+1], 0.f);
    float y2 = fmaxf((v[u*4+2]-m)*rs*lnw[h*D_HID+f+2] + lnb[h*D_HID+f+2], 0.f);
    float y3 = fmaxf((v[u*4+3]-m)*rs*lnw[h*D_HID+f+3] + lnb[h*D_HID+f+3], 0.f);
    pk.x = f2bf(y0); pk.y = f2bf(y1); pk.z = f2bf(y2); pk.w = f2bf(y3);
    int chunk = f >> 6;
    int ob = (f & 63)*2;
    if (r1 >= 0)
      *(u16x4*)((char*)A2 + (size_t)r1*(D_HID*2) + (size_t)chunk*128 + (ob ^ (((int)r1 & 7) << 4))) = pk;
    if (r2 >= 0)
      *(u16x4*)((char*)A2 + (size_t)r2*(D_HID*2) + (size_t)chunk*128 + (ob ^ (((int)r2 & 7) << 4))) = pk;
  }
}

// ---- 8) final: sum 4 GEMM2 partials + residual + LayerNorm ---------------
__global__ __launch_bounds__(256)
void k_final(const unsigned short* __restrict__ H2p, const float* __restrict__ x,
             const int* __restrict__ tokE1, const int* __restrict__ tokE2,
             const int* __restrict__ tokP1, const int* __restrict__ tokP2,
             const float* __restrict__ tokG1, const float* __restrict__ tokG2,
             const float* __restrict__ lnw, const float* __restrict__ lnb,
             float* __restrict__ out) {
  const size_t PSTR = (size_t)E_*MR*D_IN;
  int tg = blockIdx.x;
  int h = tg >> 11, s = tg & 2047;
  int bi = s >> 9, ni = s & 511;
  size_t xoff = ((size_t)bi*SEQ + (size_t)h*NSUB + ni) * D_IN;
  int p1 = tokP1[tg], p2 = tokP2[tg];
  float g1 = tokG1[tg], g2 = tokG2[tg];
  int t = threadIdx.x;
  int f = t*4;
  f32x4 xv = *(const f32x4*)(x + xoff + f);
  float v0 = xv.x, v1 = xv.y, v2 = xv.z, v3 = xv.w;
  if (p1 >= 0) {
    size_t r1 = (size_t)tokE1[tg]*MR + h*CAP + p1;
    float a0 = 0.f, a1 = 0.f, a2 = 0.f, a3 = 0.f;
    #pragma unroll
    for (int p = 0; p < KSPL2; ++p) {
      u16x4 q = *(const u16x4*)(H2p + p*PSTR + r1*D_IN + f);
      a0 += bf2f(q.x); a1 += bf2f(q.y); a2 += bf2f(q.z); a3 += bf2f(q.w);
    }
    v0 += g1*a0; v1 += g1*a1; v2 += g1*a2; v3 += g1*a3;
  }
  if (p2 >= 0) {
    size_t r2 = (size_t)tokE2[tg]*MR + h*CAP + p2;
    float a0 = 0.f, a1 = 0.f, a2 = 0.f, a3 = 0.f;
    #pragma unroll
    for (int p = 0; p < KSPL2; ++p) {
      u16x4 q = *(const u16x4*)(H2p + p*PSTR + r2*D_IN + f);
      a0 += bf2f(q.x); a1 += bf2f(q.y); a2 += bf2f(q.z); a3 += bf2f(q.w);
    }
    v0 += g2*a0; v1 += g2*a1; v2 += g2*a2; v3 += g2*a3;
  }
  float sum = v0+v1+v2+v3, sq = v0*v0+v1*v1+v2*v2+v3*v3;
  #pragma unroll
  for (int o = 32; o; o >>= 1) { sum += __shfl_xor(sum, o); sq += __shfl_xor(sq, o); }
  __shared__ float redA[4], redB[4];
  int wid = t >> 6;
  if ((t & 63) == 0) { redA[wid] = sum; redB[wid] = sq; }
  __syncthreads();
  float S = redA[0] + redA[1] + redA[2] + redA[3];
  float Q = redB[0] + redB[1] + redB[2] + redB[3];
  float m = S * (1.f / D_IN);
  float var = Q * (1.f / D_IN) - m*m;
  float rs = rsqrtf(var + 1e-6f);
  f32x4 res;
  res.x = (v0 - m)*rs*lnw[f+0] + lnb[f+0];
  res.y = (v1 - m)*rs*lnw[f+1] + lnb[f+1];
  res.z = (v2 - m)*rs*lnw[f+2] + lnb[f+2];
  res.w = (v3 - m)*rs*lnw[f+3] + lnb[f+3];
  *(f32x4*)(out + xoff + f) = res;
}

// ---- launcher ------------------------------------------------------------
extern "C" void kernel_launch(void* const* d_in, const int* in_sizes, int n_in,
                              void* d_out, int out_size, void* d_ws, size_t ws_size,
                              hipStream_t stream) {
  const float* x    = (const float*)d_in[0];
  const float* Wg   = (const float*)d_in[1];
  const float* W1   = (const float*)d_in[2];
  const float* b1   = (const float*)d_in[3];
  const float* W2   = (const float*)d_in[4];
  const float* b2   = (const float*)d_in[5];
  const float* lnhw = (const float*)d_in[6];
  const float* lnhb = (const float*)d_in[7];
  const float* lnow = (const float*)d_in[8];
  const float* lnob = (const float*)d_in[9];
  float* out = (float*)d_out;
  (void)in_sizes; (void)n_in; (void)out_size; (void)ws_size;

  char* ws = (char*)d_ws;
  size_t off = 0;
  auto take = [&](size_t bytes) -> char* {
    char* p = ws + off;
    off += (bytes + 255) & ~(size_t)255;
    return p;
  };
  int*   tokE1 = (int*)take(NTOKG*sizeof(int));
  int*   tokE2 = (int*)take(NTOKG*sizeof(int));
  int*   tokP1 = (int*)take(NTOKG*sizeof(int));
  int*   tokP2 = (int*)take(NTOKG*sizeof(int));
  float* tokG1 = (float*)take(NTOKG*sizeof(float));
  float* tokG2 = (float*)take(NTOKG*sizeof(float));
  int*   slotTok = (int*)take((size_t)E_*MR*sizeof(int));
  unsigned short* A1 = (unsigned short*)take((size_t)E_*MR*D_IN*2);   //  37.7 MB
  unsigned short* H1 = (unsigned short*)take((size_t)E_*MR*D_HID*2);  // 151 MB (= 4x GEMM2 partials)
  unsigned short* A2 = (unsigned short*)take((size_t)E_*MR*D_HID*2);  // 151 MB
  unsigned short* H2p = H1;   // GEMM2 partials alias dead H1 (after combine_ln)

  k_init_slots<<<dim3(E_*MR/256), dim3(256), 0, stream>>>(slotTok);
  k_gating<<<dim3(NTOKG), dim3(64), 0, stream>>>(x, Wg, tokE1, tokE2, tokG1, tokG2);
  k_scan<<<dim3(HGRP), dim3(64), 0, stream>>>(tokE1, tokE2, tokG1, tokG2, tokP1, tokP2, slotTok);
  k_gather1<<<dim3(E_*MR), dim3(256), 0, stream>>>(x, slotTok, A1);
  k_gemm<D_IN, D_IN, D_HID><<<dim3(E_*(D_HID/256)*MTILE), dim3(512), 0, stream>>>(A1, W1, b1, H1);
  k_zero_empty<<<dim3(E_*MR), dim3(256), 0, stream>>>(slotTok, A2);
  k_combine_ln<<<dim3(NTOKG), dim3(256), 0, stream>>>(H1, tokE1, tokE2, tokP1, tokP2,
                                                      tokG1, tokG2, lnhw, lnhb, A2);
  k_gemm<D_HID, D_IN, D_IN><<<dim3(E_*(D_IN/256)*MTILE*KSPL2), dim3(512), 0, stream>>>(A2, W2, b2, H2p);
  k_final<<<dim3(NTOKG), dim3(256), 0, stream>>>(H2p, x, tokE1, tokE2, tokP1, tokP2,
                                                 tokG1, tokG2, lnow, lnob, out);
}